// Round 1
// baseline (1083.026 us; speedup 1.0000x reference)
//
#include <hip/hip_runtime.h>

#define NUM_USERS 100000
#define NUM_ITEMS 150000
#define NN (NUM_USERS + NUM_ITEMS)   // 250000
#define EMBED_DIM 64
#define NNZ_TOT 4000000
#define D4 (EMBED_DIM / 4)           // 16 float4 per row

// ---------------- init: x_cur = concat(user, item); acc(d_out) = same ----------------
__global__ __launch_bounds__(256) void lg_init(const float* __restrict__ ue,
                                               const float* __restrict__ ie,
                                               float* __restrict__ xa,
                                               float* __restrict__ acc) {
    int i = blockIdx.x * 256 + threadIdx.x;           // float4 index, total NN*16 = 4M
    if (i >= NN * D4) return;
    float4 v;
    if (i < NUM_USERS * D4) v = ((const float4*)ue)[i];
    else                    v = ((const float4*)ie)[i - NUM_USERS * D4];
    ((float4*)xa)[i]  = v;
    ((float4*)acc)[i] = v;
}

// ---------------- CSR build ----------------
__global__ __launch_bounds__(256) void lg_hist(const int* __restrict__ rows,
                                               int* __restrict__ counts) {
    int e = blockIdx.x * 256 + threadIdx.x;
    if (e < NNZ_TOT) atomicAdd(&counts[rows[e]], 1);
}

// chunk-local exclusive scan (256/block) + block sums
__global__ __launch_bounds__(256) void lg_scan1(const int* __restrict__ counts,
                                                int* __restrict__ row_start,
                                                int* __restrict__ bsums, int n) {
    __shared__ int sm[256];
    int t = threadIdx.x;
    int i = blockIdx.x * 256 + t;
    int v = (i < n) ? counts[i] : 0;
    sm[t] = v;
    __syncthreads();
    for (int off = 1; off < 256; off <<= 1) {
        int add = (t >= off) ? sm[t - off] : 0;
        __syncthreads();
        sm[t] += add;
        __syncthreads();
    }
    int incl = sm[t];
    if (i < n) row_start[i] = incl - v;               // exclusive within chunk
    if (t == 255) bsums[blockIdx.x] = incl;           // chunk total
}

// single-block exclusive scan of block sums (nb <= 1024)
__global__ __launch_bounds__(1024) void lg_scan2(int* __restrict__ bsums, int nb) {
    __shared__ int sm[1024];
    int t = threadIdx.x;
    int v = (t < nb) ? bsums[t] : 0;
    sm[t] = v;
    __syncthreads();
    for (int off = 1; off < 1024; off <<= 1) {
        int add = (t >= off) ? sm[t - off] : 0;
        __syncthreads();
        sm[t] += add;
        __syncthreads();
    }
    if (t < nb) bsums[t] = sm[t] - v;                 // exclusive offsets
}

// add chunk offsets; copy into row_fill; write sentinel
__global__ __launch_bounds__(256) void lg_scan3(int* __restrict__ row_start,
                                                int* __restrict__ row_fill,
                                                const int* __restrict__ bsums, int n) {
    int i = blockIdx.x * 256 + threadIdx.x;
    if (i < n) {
        int v = row_start[i] + bsums[blockIdx.x];
        row_start[i] = v;
        row_fill[i]  = v;
    }
    if (i == 0) row_start[n] = NNZ_TOT;
}

__global__ __launch_bounds__(256) void lg_scatter(const int* __restrict__ rows,
                                                  const int* __restrict__ cols,
                                                  const float* __restrict__ vals,
                                                  int* __restrict__ row_fill,
                                                  int* __restrict__ cols_s,
                                                  float* __restrict__ vals_s) {
    int e = blockIdx.x * 256 + threadIdx.x;
    if (e >= NNZ_TOT) return;
    int r = rows[e];
    int p = atomicAdd(&row_fill[r], 1);
    cols_s[p] = cols[e];
    vals_s[p] = vals[e];
}

// ---------------- SpMM (CSR, quarter-wave per row, float4 per lane) ----------------
// acc[row] += sum; if final: acc *= 0.25 and skip x_out write.
__global__ __launch_bounds__(256) void lg_spmm(const int* __restrict__ row_start,
                                               const int* __restrict__ cols_s,
                                               const float* __restrict__ vals_s,
                                               const float* __restrict__ x_in,
                                               float* __restrict__ x_out,
                                               float* __restrict__ acc,
                                               int final_flag) {
    int row  = blockIdx.x * 16 + (threadIdx.x >> 4);
    int lane = threadIdx.x & 15;
    if (row >= NN) return;
    int s = row_start[row];
    int e = row_start[row + 1];
    const float4* xin4 = (const float4*)x_in;
    float4 sum = make_float4(0.f, 0.f, 0.f, 0.f);
    int i = s;
    // 2-wide unroll: two independent gathers in flight
    for (; i + 1 < e; i += 2) {
        int   c0 = cols_s[i];
        int   c1 = cols_s[i + 1];
        float v0 = vals_s[i];
        float v1 = vals_s[i + 1];
        float4 a = xin4[c0 * D4 + lane];
        float4 b = xin4[c1 * D4 + lane];
        sum.x += v0 * a.x; sum.y += v0 * a.y; sum.z += v0 * a.z; sum.w += v0 * a.w;
        sum.x += v1 * b.x; sum.y += v1 * b.y; sum.z += v1 * b.z; sum.w += v1 * b.w;
    }
    if (i < e) {
        int   c0 = cols_s[i];
        float v0 = vals_s[i];
        float4 a = xin4[c0 * D4 + lane];
        sum.x += v0 * a.x; sum.y += v0 * a.y; sum.z += v0 * a.z; sum.w += v0 * a.w;
    }
    int idx = row * D4 + lane;
    if (!final_flag) ((float4*)x_out)[idx] = sum;
    float4 acv = ((float4*)acc)[idx];
    acv.x += sum.x; acv.y += sum.y; acv.z += sum.z; acv.w += sum.w;
    if (final_flag) { acv.x *= 0.25f; acv.y *= 0.25f; acv.z *= 0.25f; acv.w *= 0.25f; }
    ((float4*)acc)[idx] = acv;
}

// ---------------- launch ----------------
extern "C" void kernel_launch(void* const* d_in, const int* in_sizes, int n_in,
                              void* d_out, int out_size, void* d_ws, size_t ws_size,
                              hipStream_t stream) {
    const float* user_emb = (const float*)d_in[0];
    const float* item_emb = (const float*)d_in[1];
    const float* adj_vals = (const float*)d_in[2];
    const int*   adj_rows = (const int*)d_in[3];
    const int*   adj_cols = (const int*)d_in[4];
    float* acc = (float*)d_out;                        // N*64 floats

    // workspace carve-up (256B aligned)
    char* ws = (char*)d_ws;
    size_t off = 0;
    auto carve = [&](size_t bytes) {
        size_t o = off;
        off += (bytes + 255) & ~size_t(255);
        return (void*)(ws + o);
    };
    float* xa        = (float*)carve(sizeof(float) * NN * EMBED_DIM);   // 64 MB
    float* xb        = (float*)carve(sizeof(float) * NN * EMBED_DIM);   // 64 MB
    int*   row_start = (int*)carve(sizeof(int) * (NN + 1));
    int*   row_fill  = (int*)carve(sizeof(int) * NN);                   // doubles as counts
    int*   cols_s    = (int*)carve(sizeof(int) * NNZ_TOT);              // 16 MB
    float* vals_s    = (float*)carve(sizeof(float) * NNZ_TOT);          // 16 MB
    int*   bsums     = (int*)carve(sizeof(int) * 1024);
    (void)ws_size; (void)in_sizes; (void)n_in; (void)out_size;

    const int nEdgeBlocks = (NNZ_TOT + 255) / 256;     // 15625
    const int nVecBlocks  = (NN * D4 + 255) / 256;     // 15625
    const int nScanBlocks = (NN + 255) / 256;          // 977
    const int nRowBlocks  = (NN + 15) / 16;            // 15625

    // build CSR
    hipMemsetAsync(row_fill, 0, sizeof(int) * NN, stream);
    lg_init<<<nVecBlocks, 256, 0, stream>>>(user_emb, item_emb, xa, acc);
    lg_hist<<<nEdgeBlocks, 256, 0, stream>>>(adj_rows, row_fill);
    lg_scan1<<<nScanBlocks, 256, 0, stream>>>(row_fill, row_start, bsums, NN);
    lg_scan2<<<1, 1024, 0, stream>>>(bsums, nScanBlocks);
    lg_scan3<<<nScanBlocks, 256, 0, stream>>>(row_start, row_fill, bsums, NN);
    lg_scatter<<<nEdgeBlocks, 256, 0, stream>>>(adj_rows, adj_cols, adj_vals,
                                                row_fill, cols_s, vals_s);

    // 3 propagation layers, acc fused
    lg_spmm<<<nRowBlocks, 256, 0, stream>>>(row_start, cols_s, vals_s, xa, xb, acc, 0);
    lg_spmm<<<nRowBlocks, 256, 0, stream>>>(row_start, cols_s, vals_s, xb, xa, acc, 0);
    lg_spmm<<<nRowBlocks, 256, 0, stream>>>(row_start, cols_s, vals_s, xa, xb, acc, 1);
}

// Round 2
// 992.363 us; speedup vs baseline: 1.0914x; 1.0914x over previous
//
#include <hip/hip_runtime.h>

#define NUM_USERS 100000
#define NUM_ITEMS 150000
#define NN (NUM_USERS + NUM_ITEMS)   // 250000
#define EMBED_DIM 64
#define NNZ_TOT 4000000
#define D4 (EMBED_DIM / 4)           // 16 float4 per row
#define BROWS 1024                   // rows per bucket
#define NBUCK ((NN + BROWS - 1) / BROWS)  // 245

// ---------------- init: xa = concat(user, item) ----------------
__global__ __launch_bounds__(256) void lg_init(const float* __restrict__ ue,
                                               const float* __restrict__ ie,
                                               float* __restrict__ xa) {
    int i = blockIdx.x * 256 + threadIdx.x;           // float4 index, total NN*16 = 4M
    if (i >= NN * D4) return;
    float4 v;
    if (i < NUM_USERS * D4) v = ((const float4*)ue)[i];
    else                    v = ((const float4*)ie)[i - NUM_USERS * D4];
    ((float4*)xa)[i] = v;
}

// ---------------- CSR build ----------------
__global__ __launch_bounds__(256) void lg_hist(const int* __restrict__ rows,
                                               int* __restrict__ counts) {
    int e = blockIdx.x * 256 + threadIdx.x;
    if (e < NNZ_TOT) atomicAdd(&counts[rows[e]], 1);
}

// chunk-local exclusive scan (256/block) + block sums
__global__ __launch_bounds__(256) void lg_scan1(const int* __restrict__ counts,
                                                int* __restrict__ row_start,
                                                int* __restrict__ bsums, int n) {
    __shared__ int sm[256];
    int t = threadIdx.x;
    int i = blockIdx.x * 256 + t;
    int v = (i < n) ? counts[i] : 0;
    sm[t] = v;
    __syncthreads();
    for (int off = 1; off < 256; off <<= 1) {
        int add = (t >= off) ? sm[t - off] : 0;
        __syncthreads();
        sm[t] += add;
        __syncthreads();
    }
    int incl = sm[t];
    if (i < n) row_start[i] = incl - v;               // exclusive within chunk
    if (t == 255) bsums[blockIdx.x] = incl;           // chunk total
}

// single-block exclusive scan of block sums (nb <= 1024)
__global__ __launch_bounds__(1024) void lg_scan2(int* __restrict__ bsums, int nb) {
    __shared__ int sm[1024];
    int t = threadIdx.x;
    int v = (t < nb) ? bsums[t] : 0;
    sm[t] = v;
    __syncthreads();
    for (int off = 1; off < 1024; off <<= 1) {
        int add = (t >= off) ? sm[t - off] : 0;
        __syncthreads();
        sm[t] += add;
        __syncthreads();
    }
    if (t < nb) bsums[t] = sm[t] - v;                 // exclusive offsets
}

// add chunk offsets; copy into row_fill; write sentinel
__global__ __launch_bounds__(256) void lg_scan3(int* __restrict__ row_start,
                                                int* __restrict__ row_fill,
                                                const int* __restrict__ bsums, int n) {
    int i = blockIdx.x * 256 + threadIdx.x;
    if (i < n) {
        int v = row_start[i] + bsums[blockIdx.x];
        row_start[i] = v;
        row_fill[i]  = v;
    }
    if (i == 0) row_start[n] = NNZ_TOT;
}

// bucket_fill[b] = row_start[b*BROWS]
__global__ __launch_bounds__(256) void lg_bucket_init(const int* __restrict__ row_start,
                                                      int* __restrict__ bucket_fill) {
    int t = threadIdx.x;
    if (t < NBUCK) bucket_fill[t] = row_start[t * BROWS];
}

// Pass B: LDS-aggregated scatter into bucket-grouped 16B records.
// Per block: histogram 4096 edges -> one global atomic per touched bucket ->
// contiguous ~270B runs per bucket (write-efficient).
__global__ __launch_bounds__(256) void lg_bucket(const int* __restrict__ rows,
                                                 const int* __restrict__ cols,
                                                 const float* __restrict__ vals,
                                                 int* __restrict__ bucket_fill,
                                                 int4* __restrict__ rec) {
    __shared__ int cnt[NBUCK];
    __shared__ int base[NBUCK];
    int t = threadIdx.x;
    for (int b = t; b < NBUCK; b += 256) cnt[b] = 0;
    __syncthreads();
    int e0 = blockIdx.x * 4096;
    #pragma unroll
    for (int k = 0; k < 16; ++k) {
        int e = e0 + k * 256 + t;
        if (e < NNZ_TOT) atomicAdd(&cnt[rows[e] >> 10], 1);
    }
    __syncthreads();
    for (int b = t; b < NBUCK; b += 256) {
        base[b] = atomicAdd(&bucket_fill[b], cnt[b]);
        cnt[b] = 0;
    }
    __syncthreads();
    #pragma unroll
    for (int k = 0; k < 16; ++k) {
        int e = e0 + k * 256 + t;
        if (e < NNZ_TOT) {
            int r = rows[e];
            int b = r >> 10;
            int loc = atomicAdd(&cnt[b], 1);
            rec[base[b] + loc] = make_int4(r, cols[e], __float_as_int(vals[e]), 0);
        }
    }
}

// Pass C: one block per bucket; exact CSR scatter confined to a ~128KB window.
__global__ __launch_bounds__(1024) void lg_csr(const int4* __restrict__ rec,
                                               const int* __restrict__ row_start,
                                               int* __restrict__ row_fill,
                                               int2* __restrict__ edge8) {
    int b = blockIdx.x;
    int lo = row_start[b * BROWS];
    int hiRow = (b + 1) * BROWS; if (hiRow > NN) hiRow = NN;
    int hi = row_start[hiRow];
    for (int e = lo + threadIdx.x; e < hi; e += 1024) {
        int4 r = rec[e];
        int p = atomicAdd(&row_fill[r.x], 1);
        edge8[p] = make_int2(r.y, r.z);
    }
}

// ---------------- SpMM (CSR, quarter-wave per row, float4 per lane) ----------------
__global__ __launch_bounds__(256) void lg_spmm(const int* __restrict__ row_start,
                                               const int2* __restrict__ edges,
                                               const float* __restrict__ x_in,
                                               float* __restrict__ x_out) {
    int row  = blockIdx.x * 16 + (threadIdx.x >> 4);
    int lane = threadIdx.x & 15;
    if (row >= NN) return;
    int s = row_start[row];
    int e = row_start[row + 1];
    const float4* xin4 = (const float4*)x_in;
    float4 sum = make_float4(0.f, 0.f, 0.f, 0.f);
    int i = s;
    for (; i + 3 < e; i += 4) {
        int2 e0 = edges[i], e1 = edges[i + 1], e2 = edges[i + 2], e3 = edges[i + 3];
        float4 a = xin4[e0.x * D4 + lane];
        float4 b = xin4[e1.x * D4 + lane];
        float4 c = xin4[e2.x * D4 + lane];
        float4 d = xin4[e3.x * D4 + lane];
        float v0 = __int_as_float(e0.y), v1 = __int_as_float(e1.y);
        float v2 = __int_as_float(e2.y), v3 = __int_as_float(e3.y);
        sum.x += v0 * a.x + v1 * b.x + v2 * c.x + v3 * d.x;
        sum.y += v0 * a.y + v1 * b.y + v2 * c.y + v3 * d.y;
        sum.z += v0 * a.z + v1 * b.z + v2 * c.z + v3 * d.z;
        sum.w += v0 * a.w + v1 * b.w + v2 * c.w + v3 * d.w;
    }
    for (; i < e; ++i) {
        int2 e0 = edges[i];
        float4 a = xin4[e0.x * D4 + lane];
        float v0 = __int_as_float(e0.y);
        sum.x += v0 * a.x; sum.y += v0 * a.y; sum.z += v0 * a.z; sum.w += v0 * a.w;
    }
    ((float4*)x_out)[row * D4 + lane] = sum;
}

// final layer: sum = x3; out = (x0 + x1 + x2 + x3) / 4
__global__ __launch_bounds__(256) void lg_spmm_final(const int* __restrict__ row_start,
                                                     const int2* __restrict__ edges,
                                                     const float* __restrict__ x2_in,
                                                     const float* __restrict__ x1,
                                                     const float* __restrict__ ue,
                                                     const float* __restrict__ ie,
                                                     float* __restrict__ out) {
    int row  = blockIdx.x * 16 + (threadIdx.x >> 4);
    int lane = threadIdx.x & 15;
    if (row >= NN) return;
    int s = row_start[row];
    int e = row_start[row + 1];
    const float4* xin4 = (const float4*)x2_in;
    float4 sum = make_float4(0.f, 0.f, 0.f, 0.f);
    int i = s;
    for (; i + 3 < e; i += 4) {
        int2 e0 = edges[i], e1 = edges[i + 1], e2 = edges[i + 2], e3 = edges[i + 3];
        float4 a = xin4[e0.x * D4 + lane];
        float4 b = xin4[e1.x * D4 + lane];
        float4 c = xin4[e2.x * D4 + lane];
        float4 d = xin4[e3.x * D4 + lane];
        float v0 = __int_as_float(e0.y), v1 = __int_as_float(e1.y);
        float v2 = __int_as_float(e2.y), v3 = __int_as_float(e3.y);
        sum.x += v0 * a.x + v1 * b.x + v2 * c.x + v3 * d.x;
        sum.y += v0 * a.y + v1 * b.y + v2 * c.y + v3 * d.y;
        sum.z += v0 * a.z + v1 * b.z + v2 * c.z + v3 * d.z;
        sum.w += v0 * a.w + v1 * b.w + v2 * c.w + v3 * d.w;
    }
    for (; i < e; ++i) {
        int2 e0 = edges[i];
        float4 a = xin4[e0.x * D4 + lane];
        float v0 = __int_as_float(e0.y);
        sum.x += v0 * a.x; sum.y += v0 * a.y; sum.z += v0 * a.z; sum.w += v0 * a.w;
    }
    int idx = row * D4 + lane;
    float4 a0 = (row < NUM_USERS) ? ((const float4*)ue)[idx]
                                  : ((const float4*)ie)[idx - NUM_USERS * D4];
    float4 a1 = ((const float4*)x1)[idx];
    float4 a2 = ((const float4*)x2_in)[idx];
    float4 o;
    o.x = (a0.x + a1.x + a2.x + sum.x) * 0.25f;
    o.y = (a0.y + a1.y + a2.y + sum.y) * 0.25f;
    o.z = (a0.z + a1.z + a2.z + sum.z) * 0.25f;
    o.w = (a0.w + a1.w + a2.w + sum.w) * 0.25f;
    ((float4*)out)[idx] = o;
}

// ---------------- launch ----------------
extern "C" void kernel_launch(void* const* d_in, const int* in_sizes, int n_in,
                              void* d_out, int out_size, void* d_ws, size_t ws_size,
                              hipStream_t stream) {
    const float* user_emb = (const float*)d_in[0];
    const float* item_emb = (const float*)d_in[1];
    const float* adj_vals = (const float*)d_in[2];
    const int*   adj_rows = (const int*)d_in[3];
    const int*   adj_cols = (const int*)d_in[4];
    float* out = (float*)d_out;                        // N*64 floats

    // workspace carve-up (256B aligned)
    char* ws = (char*)d_ws;
    size_t off = 0;
    auto carve = [&](size_t bytes) {
        size_t o = off;
        off += (bytes + 255) & ~size_t(255);
        return (void*)(ws + o);
    };
    float* xa        = (float*)carve(sizeof(float) * NN * EMBED_DIM);   // 64 MB (x0, then x2)
    float* xb        = (float*)carve(sizeof(float) * NN * EMBED_DIM);   // 64 MB (x1); aliases rec16
    int2*  edge8     = (int2*)carve(sizeof(int2) * NNZ_TOT);            // 32 MB
    int*   row_start = (int*)carve(sizeof(int) * (NN + 1));
    int*   row_fill  = (int*)carve(sizeof(int) * NN);                   // doubles as counts
    int*   bucket_fill = (int*)carve(sizeof(int) * NBUCK);
    int*   bsums     = (int*)carve(sizeof(int) * 1024);
    int4*  rec16     = (int4*)xb;   // alias: rec16 dead before xb is first written
    (void)ws_size; (void)in_sizes; (void)n_in; (void)out_size;

    const int nEdgeBlocks  = (NNZ_TOT + 255) / 256;        // 15625
    const int nVecBlocks   = (NN * D4 + 255) / 256;        // 15625
    const int nScanBlocks  = (NN + 255) / 256;             // 977
    const int nRowBlocks   = (NN + 15) / 16;               // 15625
    const int nBucketBlocks = (NNZ_TOT + 4095) / 4096;     // 977

    // build CSR (two-level scatter for write locality)
    hipMemsetAsync(row_fill, 0, sizeof(int) * NN, stream);
    lg_init<<<nVecBlocks, 256, 0, stream>>>(user_emb, item_emb, xa);
    lg_hist<<<nEdgeBlocks, 256, 0, stream>>>(adj_rows, row_fill);
    lg_scan1<<<nScanBlocks, 256, 0, stream>>>(row_fill, row_start, bsums, NN);
    lg_scan2<<<1, 1024, 0, stream>>>(bsums, nScanBlocks);
    lg_scan3<<<nScanBlocks, 256, 0, stream>>>(row_start, row_fill, bsums, NN);
    lg_bucket_init<<<1, 256, 0, stream>>>(row_start, bucket_fill);
    lg_bucket<<<nBucketBlocks, 256, 0, stream>>>(adj_rows, adj_cols, adj_vals,
                                                 bucket_fill, rec16);
    lg_csr<<<NBUCK, 1024, 0, stream>>>(rec16, row_start, row_fill, edge8);

    // 3 propagation layers; final layer fuses (x0+x1+x2+x3)/4
    lg_spmm<<<nRowBlocks, 256, 0, stream>>>(row_start, edge8, xa, xb);        // x1
    lg_spmm<<<nRowBlocks, 256, 0, stream>>>(row_start, edge8, xb, xa);        // x2
    lg_spmm_final<<<nRowBlocks, 256, 0, stream>>>(row_start, edge8, xa, xb,
                                                  user_emb, item_emb, out);   // out
}

// Round 3
// 536.058 us; speedup vs baseline: 2.0204x; 1.8512x over previous
//
#include <hip/hip_runtime.h>
#include <hip/hip_fp16.h>

#define NUM_USERS 100000
#define NUM_ITEMS 150000
#define NN (NUM_USERS + NUM_ITEMS)   // 250000
#define EMBED_DIM 64
#define NNZ_TOT 4000000
#define D4 16                        // float4 chunks per row
#define BROWS 1024                   // rows per bucket
#define NBUCK 245                    // ceil(NN / BROWS)
#define EPB 4096                     // edges per block in build passes
#define NBLK 977                     // ceil(NNZ / EPB)
#define HISTN (NBUCK * NBLK)         // 239365

struct __align__(8) h4 { __half2 a, b; };   // 4 halfs = 8 B (one row chunk per lane)

// ---------------- fp16 copy of concat(user,item) ----------------
__global__ __launch_bounds__(256) void lg_cvt(const float* __restrict__ ue,
                                              const float* __restrict__ ie,
                                              h4* __restrict__ x0h) {
    int i = blockIdx.x * 256 + threadIdx.x;          // chunk index, NN*16 total
    if (i >= NN * D4) return;
    float4 v;
    if (i < NUM_USERS * D4) v = ((const float4*)ue)[i];
    else                    v = ((const float4*)ie)[i - NUM_USERS * D4];
    h4 o;
    o.a = __floats2half2_rn(v.x, v.y);
    o.b = __floats2half2_rn(v.z, v.w);
    x0h[i] = o;
}

// ---------------- Pass A: per-block per-bucket histogram (LDS only) ----------------
__global__ __launch_bounds__(256) void lg_histA(const int* __restrict__ rows,
                                                int* __restrict__ histG) {
    __shared__ int cnt[NBUCK];
    int t = threadIdx.x;
    for (int j = t; j < NBUCK; j += 256) cnt[j] = 0;
    __syncthreads();
    int e0 = blockIdx.x * EPB;
    #pragma unroll
    for (int k = 0; k < 16; ++k) {
        int e = e0 + k * 256 + t;
        if (e < NNZ_TOT) atomicAdd(&cnt[rows[e] >> 10], 1);
    }
    __syncthreads();
    for (int j = t; j < NBUCK; j += 256) histG[j * NBLK + blockIdx.x] = cnt[j];
}

// ---------------- scan over HISTN ints: chunk scan + block-sum scan + add ----------------
__global__ __launch_bounds__(256) void lg_scan1(const int* __restrict__ in,
                                                int* __restrict__ out,
                                                int* __restrict__ bsums, int n) {
    __shared__ int sm[256];
    int t = threadIdx.x;
    int i = blockIdx.x * 256 + t;
    int v = (i < n) ? in[i] : 0;
    sm[t] = v;
    __syncthreads();
    for (int off = 1; off < 256; off <<= 1) {
        int add = (t >= off) ? sm[t - off] : 0;
        __syncthreads();
        sm[t] += add;
        __syncthreads();
    }
    if (i < n) out[i] = sm[t] - v;                  // exclusive within chunk
    if (t == 255) bsums[blockIdx.x] = sm[t];
}

__global__ __launch_bounds__(1024) void lg_scan2(int* __restrict__ bsums, int nb) {
    __shared__ int sm[1024];
    int t = threadIdx.x;
    int v = (t < nb) ? bsums[t] : 0;
    sm[t] = v;
    __syncthreads();
    for (int off = 1; off < 1024; off <<= 1) {
        int add = (t >= off) ? sm[t - off] : 0;
        __syncthreads();
        sm[t] += add;
        __syncthreads();
    }
    if (t < nb) bsums[t] = sm[t] - v;               // exclusive offsets
}

__global__ __launch_bounds__(256) void lg_scan3(int* __restrict__ data,
                                                const int* __restrict__ bsums, int n) {
    int i = blockIdx.x * 256 + threadIdx.x;
    if (i < n) data[i] += bsums[blockIdx.x];
}

// ---------------- Pass B: deterministic bucket-grouped scatter, 8 B records ----------------
__global__ __launch_bounds__(256) void lg_scatB(const int* __restrict__ rows,
                                                const int* __restrict__ cols,
                                                const float* __restrict__ vals,
                                                const int* __restrict__ baseG,
                                                int2* __restrict__ rec) {
    __shared__ int cnt[NBUCK];
    __shared__ int base[NBUCK];
    int t = threadIdx.x, b = blockIdx.x;
    for (int j = t; j < NBUCK; j += 256) { cnt[j] = 0; base[j] = baseG[j * NBLK + b]; }
    __syncthreads();
    int e0 = b * EPB;
    #pragma unroll
    for (int k = 0; k < 16; ++k) {
        int e = e0 + k * 256 + t;
        if (e < NNZ_TOT) {
            int r = rows[e];
            int j = r >> 10;
            int loc = atomicAdd(&cnt[j], 1);
            // packed: col in high 18 bits, row_local in low 10 bits
            rec[base[j] + loc] = make_int2((cols[e] << 10) | (r & 1023),
                                           __float_as_int(vals[e]));
        }
    }
}

// ---------------- Pass C: per-bucket CSR finalize (LDS hist + scan + scatter) ----------------
__global__ __launch_bounds__(1024) void lg_csrC(const int2* __restrict__ rec,
                                                const int* __restrict__ baseG,
                                                int* __restrict__ row_start,
                                                int2* __restrict__ edge8) {
    __shared__ int sm[1024];
    int j = blockIdx.x, t = threadIdx.x;
    int lo = baseG[j * NBLK];
    int hi = (j + 1 < NBUCK) ? baseG[(j + 1) * NBLK] : NNZ_TOT;
    sm[t] = 0;
    __syncthreads();
    for (int e = lo + t; e < hi; e += 1024) atomicAdd(&sm[rec[e].x & 1023], 1);
    __syncthreads();
    int v = sm[t];
    for (int off = 1; off < 1024; off <<= 1) {
        int add = (t >= off) ? sm[t - off] : 0;
        __syncthreads();
        sm[t] += add;
        __syncthreads();
    }
    int excl = sm[t] - v;
    int grow = j * BROWS + t;
    if (grow <= NN) row_start[grow] = lo + excl;    // covers sentinel at grow == NN
    __syncthreads();
    sm[t] = excl;                                   // becomes fill counter
    __syncthreads();
    for (int e = lo + t; e < hi; e += 1024) {
        int2 r = rec[e];                            // L2-hot (131 KB window, 2nd sweep)
        int pos = lo + atomicAdd(&sm[r.x & 1023], 1);
        edge8[pos] = make_int2(r.x >> 10, r.y);     // (col, val-bits)
    }
}

// ---------------- SpMM: quarter-wave per row, fp16 gather, fp32 accumulate ----------------
__global__ __launch_bounds__(256) void lg_spmmH(const int* __restrict__ row_start,
                                                const int2* __restrict__ edges,
                                                const h4* __restrict__ xin,
                                                h4* __restrict__ xout) {
    int row  = blockIdx.x * 16 + (threadIdx.x >> 4);
    int lane = threadIdx.x & 15;
    if (row >= NN) return;
    int s = row_start[row];
    int e = row_start[row + 1];
    float4 sum = make_float4(0.f, 0.f, 0.f, 0.f);
    int i = s;
    for (; i + 3 < e; i += 4) {
        int2 e0 = edges[i], e1 = edges[i + 1], e2 = edges[i + 2], e3 = edges[i + 3];
        h4 A = xin[e0.x * D4 + lane];
        h4 B = xin[e1.x * D4 + lane];
        h4 C = xin[e2.x * D4 + lane];
        h4 D = xin[e3.x * D4 + lane];
        float v0 = __int_as_float(e0.y), v1 = __int_as_float(e1.y);
        float v2 = __int_as_float(e2.y), v3 = __int_as_float(e3.y);
        float2 a0 = __half22float2(A.a), a1 = __half22float2(A.b);
        float2 b0 = __half22float2(B.a), b1 = __half22float2(B.b);
        float2 c0 = __half22float2(C.a), c1 = __half22float2(C.b);
        float2 d0 = __half22float2(D.a), d1 = __half22float2(D.b);
        sum.x += v0 * a0.x + v1 * b0.x + v2 * c0.x + v3 * d0.x;
        sum.y += v0 * a0.y + v1 * b0.y + v2 * c0.y + v3 * d0.y;
        sum.z += v0 * a1.x + v1 * b1.x + v2 * c1.x + v3 * d1.x;
        sum.w += v0 * a1.y + v1 * b1.y + v2 * c1.y + v3 * d1.y;
    }
    for (; i < e; ++i) {
        int2 e0 = edges[i];
        h4 A = xin[e0.x * D4 + lane];
        float v0 = __int_as_float(e0.y);
        float2 a0 = __half22float2(A.a), a1 = __half22float2(A.b);
        sum.x += v0 * a0.x; sum.y += v0 * a0.y; sum.z += v0 * a1.x; sum.w += v0 * a1.y;
    }
    h4 o;
    o.a = __floats2half2_rn(sum.x, sum.y);
    o.b = __floats2half2_rn(sum.z, sum.w);
    xout[row * D4 + lane] = o;
}

// final layer: x3 = A*x2 (fp16 gather); out = (x0_fp32 + x1 + x2 + x3) / 4
__global__ __launch_bounds__(256) void lg_finalH(const int* __restrict__ row_start,
                                                 const int2* __restrict__ edges,
                                                 const h4* __restrict__ x2h,
                                                 const h4* __restrict__ x1h,
                                                 const float* __restrict__ ue,
                                                 const float* __restrict__ ie,
                                                 float* __restrict__ out) {
    int row  = blockIdx.x * 16 + (threadIdx.x >> 4);
    int lane = threadIdx.x & 15;
    if (row >= NN) return;
    int s = row_start[row];
    int e = row_start[row + 1];
    float4 sum = make_float4(0.f, 0.f, 0.f, 0.f);
    int i = s;
    for (; i + 3 < e; i += 4) {
        int2 e0 = edges[i], e1 = edges[i + 1], e2 = edges[i + 2], e3 = edges[i + 3];
        h4 A = x2h[e0.x * D4 + lane];
        h4 B = x2h[e1.x * D4 + lane];
        h4 C = x2h[e2.x * D4 + lane];
        h4 D = x2h[e3.x * D4 + lane];
        float v0 = __int_as_float(e0.y), v1 = __int_as_float(e1.y);
        float v2 = __int_as_float(e2.y), v3 = __int_as_float(e3.y);
        float2 a0 = __half22float2(A.a), a1 = __half22float2(A.b);
        float2 b0 = __half22float2(B.a), b1 = __half22float2(B.b);
        float2 c0 = __half22float2(C.a), c1 = __half22float2(C.b);
        float2 d0 = __half22float2(D.a), d1 = __half22float2(D.b);
        sum.x += v0 * a0.x + v1 * b0.x + v2 * c0.x + v3 * d0.x;
        sum.y += v0 * a0.y + v1 * b0.y + v2 * c0.y + v3 * d0.y;
        sum.z += v0 * a1.x + v1 * b1.x + v2 * c1.x + v3 * d1.x;
        sum.w += v0 * a1.y + v1 * b1.y + v2 * c1.y + v3 * d1.y;
    }
    for (; i < e; ++i) {
        int2 e0 = edges[i];
        h4 A = x2h[e0.x * D4 + lane];
        float v0 = __int_as_float(e0.y);
        float2 a0 = __half22float2(A.a), a1 = __half22float2(A.b);
        sum.x += v0 * a0.x; sum.y += v0 * a0.y; sum.z += v0 * a1.x; sum.w += v0 * a1.y;
    }
    int idx = row * D4 + lane;
    float4 a0 = (row < NUM_USERS) ? ((const float4*)ue)[idx]
                                  : ((const float4*)ie)[idx - NUM_USERS * D4];
    h4 h1 = x1h[idx], h2 = x2h[idx];
    float2 p0 = __half22float2(h1.a), p1 = __half22float2(h1.b);
    float2 q0 = __half22float2(h2.a), q1 = __half22float2(h2.b);
    float4 o;
    o.x = (a0.x + p0.x + q0.x + sum.x) * 0.25f;
    o.y = (a0.y + p0.y + q0.y + sum.y) * 0.25f;
    o.z = (a0.z + p1.x + q1.x + sum.z) * 0.25f;
    o.w = (a0.w + p1.y + q1.y + sum.w) * 0.25f;
    ((float4*)out)[idx] = o;
}

// ---------------- launch ----------------
extern "C" void kernel_launch(void* const* d_in, const int* in_sizes, int n_in,
                              void* d_out, int out_size, void* d_ws, size_t ws_size,
                              hipStream_t stream) {
    const float* user_emb = (const float*)d_in[0];
    const float* item_emb = (const float*)d_in[1];
    const float* adj_vals = (const float*)d_in[2];
    const int*   adj_rows = (const int*)d_in[3];
    const int*   adj_cols = (const int*)d_in[4];
    float* out = (float*)d_out;

    char* ws = (char*)d_ws;
    size_t off = 0;
    auto carve = [&](size_t bytes) {
        size_t o = off;
        off += (bytes + 255) & ~size_t(255);
        return (void*)(ws + o);
    };
    h4*   x0h       = (h4*)carve(sizeof(h4) * NN * D4);        // 32 MB
    int2* rec       = (int2*)carve(sizeof(int2) * NNZ_TOT);    // 32 MB (aliases x1h)
    h4*   x1h       = (h4*)rec;                                // rec dead before x1 written
    h4*   x2h       = (h4*)carve(sizeof(h4) * NN * D4);        // 32 MB
    int2* edge8     = (int2*)carve(sizeof(int2) * NNZ_TOT);    // 32 MB
    int*  histG     = (int*)carve(sizeof(int) * HISTN);        // 936 KB
    int*  baseG     = (int*)carve(sizeof(int) * HISTN);        // 936 KB
    int*  row_start = (int*)carve(sizeof(int) * (NN + 1));     // 1 MB
    int*  bsums     = (int*)carve(sizeof(int) * 1024);
    (void)ws_size; (void)in_sizes; (void)n_in; (void)out_size;

    const int nVecBlocks  = (NN * D4 + 255) / 256;             // 15625
    const int nRowBlocks  = (NN + 15) / 16;                    // 15625
    const int nScanBlocks = (HISTN + 255) / 256;               // 936

    lg_cvt<<<nVecBlocks, 256, 0, stream>>>(user_emb, item_emb, x0h);
    lg_histA<<<NBLK, 256, 0, stream>>>(adj_rows, histG);
    lg_scan1<<<nScanBlocks, 256, 0, stream>>>(histG, baseG, bsums, HISTN);
    lg_scan2<<<1, 1024, 0, stream>>>(bsums, nScanBlocks);
    lg_scan3<<<nScanBlocks, 256, 0, stream>>>(baseG, bsums, HISTN);
    lg_scatB<<<NBLK, 256, 0, stream>>>(adj_rows, adj_cols, adj_vals, baseG, rec);
    lg_csrC<<<NBUCK, 1024, 0, stream>>>(rec, baseG, row_start, edge8);

    lg_spmmH<<<nRowBlocks, 256, 0, stream>>>(row_start, edge8, x0h, x1h);   // x1
    lg_spmmH<<<nRowBlocks, 256, 0, stream>>>(row_start, edge8, x1h, x2h);   // x2
    lg_finalH<<<nRowBlocks, 256, 0, stream>>>(row_start, edge8, x2h, x1h,
                                              user_emb, item_emb, out);     // out
}